// Round 5
// baseline (255.146 us; speedup 1.0000x reference)
//
#include <hip/hip_runtime.h>
#include <hip/hip_bf16.h>
#include <cstdint>

constexpr int N_NODES = 50000;
constexpr int N_EDGES = 800000;
constexpr int F_IN    = 128;
constexpr int F_HID   = 256;
constexpr int N_COLS  = 256;
constexpr int M_PAD   = 50048;   // 782 * 64
constexpr int NB_SCAN = (N_NODES + 255) / 256;   // 196 blocks

typedef unsigned short u16;
typedef u16   ushort4v __attribute__((ext_vector_type(4)));
typedef u16   ushort8v __attribute__((ext_vector_type(8)));
typedef __bf16 bf16x8  __attribute__((ext_vector_type(8)));
typedef float  f32x4   __attribute__((ext_vector_type(4)));

__device__ __forceinline__ float bf2f(u16 u) {
    return __uint_as_float(((uint32_t)u) << 16);
}
__device__ __forceinline__ u16 f2bf(float f) {
    uint32_t u = __float_as_uint(f);
    uint32_t r = u + 0x7FFFu + ((u >> 16) & 1u);   // RNE
    return (u16)(r >> 16);
}

// async global->LDS, 16B per lane. LDS dest is wave-uniform base; HW adds lane*16.
__device__ __forceinline__ void gll16(const void* g, void* l) {
    __builtin_amdgcn_global_load_lds(
        (const __attribute__((address_space(1))) uint32_t*)(uintptr_t)g,
        (__attribute__((address_space(3))) uint32_t*)(uintptr_t)l,
        16, 0, 0);
}

// ---------------------------------------------------------------------------
// CSR build
// ---------------------------------------------------------------------------
__global__ void deg_kernel(const int* __restrict__ dst, int* __restrict__ deg) {
    int e = blockIdx.x * blockDim.x + threadIdx.x;
    if (e < N_EDGES) atomicAdd(&deg[dst[e]], 1);
}

__global__ __launch_bounds__(256) void block_sum_kernel(const int* __restrict__ deg,
                                                        int* __restrict__ part) {
    const int n = blockIdx.x * 256 + threadIdx.x;
    int v = (n < N_NODES) ? deg[n] : 0;
    #pragma unroll
    for (int o = 32; o > 0; o >>= 1) v += __shfl_down(v, o, 64);
    __shared__ int s[4];
    if ((threadIdx.x & 63) == 0) s[threadIdx.x >> 6] = v;
    __syncthreads();
    if (threadIdx.x == 0) part[blockIdx.x] = s[0] + s[1] + s[2] + s[3];
}

__global__ __launch_bounds__(256) void part_scan_kernel(int* __restrict__ part,
                                                        int* __restrict__ row_ptr) {
    __shared__ int s[256];
    const int tid = threadIdx.x;
    int v = (tid < NB_SCAN) ? part[tid] : 0;
    s[tid] = v;
    __syncthreads();
    #pragma unroll
    for (int o = 1; o < 256; o <<= 1) {
        int t = 0;
        if (tid >= o) t = s[tid - o];
        __syncthreads();
        s[tid] += t;
        __syncthreads();
    }
    if (tid < NB_SCAN) part[tid] = s[tid] - v;
    if (tid == 255) row_ptr[N_NODES] = s[255];
}

__global__ __launch_bounds__(256) void row_ptr_kernel(const int* __restrict__ deg,
                                                      const int* __restrict__ part,
                                                      int* __restrict__ row_ptr,
                                                      float* __restrict__ inv_deg) {
    __shared__ int s[256];
    const int tid = threadIdx.x;
    const int n = blockIdx.x * 256 + tid;
    const int d = (n < N_NODES) ? deg[n] : 0;
    s[tid] = d;
    __syncthreads();
    #pragma unroll
    for (int o = 1; o < 256; o <<= 1) {
        int t = 0;
        if (tid >= o) t = s[tid - o];
        __syncthreads();
        s[tid] += t;
        __syncthreads();
    }
    if (n < N_NODES) {
        row_ptr[n] = part[blockIdx.x] + s[tid] - d;
        inv_deg[n] = (d > 0) ? (1.0f / (float)d) : 0.0f;
    }
}

__global__ void fill_kernel(const int* __restrict__ src, const int* __restrict__ dst,
                            const int* __restrict__ row_ptr, int* __restrict__ cursor,
                            int* __restrict__ col) {
    int e = blockIdx.x * blockDim.x + threadIdx.x;
    if (e < N_EDGES) {
        int d = dst[e];
        int pos = atomicAdd(&cursor[d], 1);
        col[row_ptr[d] + pos] = src[e];
    }
}

// ---------------------------------------------------------------------------
// fp32 -> bf16 convert
// ---------------------------------------------------------------------------
__global__ __launch_bounds__(256) void f2bf_kernel(const float* __restrict__ in,
                                                   u16* __restrict__ out, int n4) {
    int i = blockIdx.x * blockDim.x + threadIdx.x;
    if (i < n4) {
        float4 v = *reinterpret_cast<const float4*>(&in[(size_t)i * 4]);
        ushort4v o;
        o.x = f2bf(v.x); o.y = f2bf(v.y); o.z = f2bf(v.z); o.w = f2bf(v.w);
        *reinterpret_cast<ushort4v*>(&out[(size_t)i * 4]) = o;
    }
}

// W [K][256] fp32 -> Wt [256][K] bf16
template <int K>
__global__ __launch_bounds__(256) void wtrans(const float* __restrict__ W,
                                              u16* __restrict__ Wt) {
    const int n = blockIdx.x;
    for (int k = threadIdx.x; k < K; k += 256)
        Wt[(size_t)n * K + k] = f2bf(W[(size_t)k * N_COLS + n]);
}

// ---------------------------------------------------------------------------
// Mean aggregation, bf16 in / bf16 out, fp32 accumulation. (at its L2-miss floor)
// ---------------------------------------------------------------------------
template <int F>
__global__ __launch_bounds__(256) void agg_mean_bf16(const u16* __restrict__ feat,
                                                     const int* __restrict__ rp,
                                                     const int* __restrict__ col,
                                                     const float* __restrict__ invd,
                                                     u16* __restrict__ out) {
    constexpr int LPN = F / 8;
    constexpr int NPB = 256 / LPN;
    const int slot = threadIdx.x / LPN;
    const int ln   = threadIdx.x % LPN;
    const int n = blockIdx.x * NPB + slot;
    if (n >= N_NODES) return;
    const int beg = rp[n], end = rp[n + 1];
    float acc0[8] = {}, acc1[8] = {};
    int e = beg;
    for (; e + 3 < end; e += 4) {
        int nb0 = col[e];
        int nb1 = col[e + 1];
        int nb2 = col[e + 2];
        int nb3 = col[e + 3];
        ushort8v v0 = *reinterpret_cast<const ushort8v*>(&feat[(size_t)nb0 * F + ln * 8]);
        ushort8v v1 = *reinterpret_cast<const ushort8v*>(&feat[(size_t)nb1 * F + ln * 8]);
        ushort8v v2 = *reinterpret_cast<const ushort8v*>(&feat[(size_t)nb2 * F + ln * 8]);
        ushort8v v3 = *reinterpret_cast<const ushort8v*>(&feat[(size_t)nb3 * F + ln * 8]);
        #pragma unroll
        for (int j = 0; j < 8; ++j) acc0[j] += bf2f(v0[j]);
        #pragma unroll
        for (int j = 0; j < 8; ++j) acc1[j] += bf2f(v1[j]);
        #pragma unroll
        for (int j = 0; j < 8; ++j) acc0[j] += bf2f(v2[j]);
        #pragma unroll
        for (int j = 0; j < 8; ++j) acc1[j] += bf2f(v3[j]);
    }
    if (e + 1 < end) {
        int nb0 = col[e];
        int nb1 = col[e + 1];
        ushort8v v0 = *reinterpret_cast<const ushort8v*>(&feat[(size_t)nb0 * F + ln * 8]);
        ushort8v v1 = *reinterpret_cast<const ushort8v*>(&feat[(size_t)nb1 * F + ln * 8]);
        #pragma unroll
        for (int j = 0; j < 8; ++j) acc0[j] += bf2f(v0[j]);
        #pragma unroll
        for (int j = 0; j < 8; ++j) acc1[j] += bf2f(v1[j]);
        e += 2;
    }
    if (e < end) {
        ushort8v v = *reinterpret_cast<const ushort8v*>(&feat[(size_t)col[e] * F + ln * 8]);
        #pragma unroll
        for (int j = 0; j < 8; ++j) acc0[j] += bf2f(v[j]);
    }
    const float s = invd[n];
    ushort8v o;
    #pragma unroll
    for (int j = 0; j < 8; ++j) o[j] = f2bf((acc0[j] + acc1[j]) * s);
    *reinterpret_cast<ushort8v*>(&out[(size_t)n * F + ln * 8]) = o;
}

// ---------------------------------------------------------------------------
// C = relu([A1 | A2] @ W + b), bf16 MFMA.
// BM=64, BN=256 (full width, A read ONCE), BK=32, 256 threads = 4 waves.
// Wave wv computes rows 0..63 x cols [wv*64, wv*64+64). 4x4 16x16 frags.
// Grid = M_PAD/64 = 782 blocks -> all co-resident (8 blocks/CU by 20KB LDS).
// ---------------------------------------------------------------------------
template <int K1, bool OUT_BF16>
__global__ __launch_bounds__(256) void gemm_bt_wide(const u16* __restrict__ A1,
                                                    const u16* __restrict__ A2,
                                                    const u16* __restrict__ Bt,
                                                    const float* __restrict__ bias,
                                                    void* __restrict__ Cout, int M) {
    constexpr int K = 2 * K1;
    __shared__ u16 As[64 * 32];     // 4 KB
    __shared__ u16 Bs[256 * 32];    // 16 KB

    const int t  = threadIdx.x;
    const int wv = t >> 6;          // wave 0..3
    const int l  = t & 63;
    const int m0 = blockIdx.x * 64;

    const int lr = l & 15;
    const int lk = (l >> 4) * 8;
    const int wc = wv * 64;         // this wave's column range

    // staging: per wave, A batch = 16 rows (1 gll), B batches = 4x16 rows.
    const int srow = l >> 2;        // 0..15 within a 16-row batch
    const int sk   = (l & 3) * 8;   // k-element offset (16B)

    f32x4 acc[4][4] = {};

    #pragma unroll 1
    for (int kt = 0; kt < K / 32; ++kt) {
        const int kg = kt * 32;
        const u16* Ab;
        int ka;
        if (kg < K1) { Ab = A1; ka = kg; }
        else         { Ab = A2; ka = kg - K1; }

        // A: rows m0 + wv*16 + srow
        gll16(&Ab[(size_t)(m0 + wv * 16 + srow) * K1 + ka + sk], &As[wv * 512]);
        // B: rows (cols of W) wv*64 + j*16 + srow
        #pragma unroll
        for (int j = 0; j < 4; ++j)
            gll16(&Bt[(size_t)(wv * 64 + j * 16 + srow) * K + kg + sk],
                  &Bs[wv * 2048 + j * 512]);
        __syncthreads();

        bf16x8 af[4], bfr[4];
        #pragma unroll
        for (int m = 0; m < 4; ++m)
            af[m] = *reinterpret_cast<const bf16x8*>(&As[(m * 16 + lr) * 32 + lk]);
        #pragma unroll
        for (int n = 0; n < 4; ++n)
            bfr[n] = *reinterpret_cast<const bf16x8*>(&Bs[(wc + n * 16 + lr) * 32 + lk]);

        #pragma unroll
        for (int m = 0; m < 4; ++m)
            #pragma unroll
            for (int n = 0; n < 4; ++n)
                acc[m][n] = __builtin_amdgcn_mfma_f32_16x16x32_bf16(af[m], bfr[n], acc[m][n], 0, 0, 0);
        __syncthreads();
    }

    // epilogue: C/D layout col = l&15 (+n*16+wc), row = (l>>4)*4 + r (+m*16)
    const int orow = (l >> 4) * 4;
    float bcol[4];
    #pragma unroll
    for (int n = 0; n < 4; ++n) bcol[n] = bias[wc + n * 16 + lr];

    #pragma unroll
    for (int m = 0; m < 4; ++m) {
        #pragma unroll
        for (int r = 0; r < 4; ++r) {
            const int row = m0 + m * 16 + orow + r;
            if (row < M) {
                #pragma unroll
                for (int n = 0; n < 4; ++n) {
                    const int cg = wc + n * 16 + lr;
                    float v = fmaxf(acc[m][n][r] + bcol[n], 0.f);
                    if (OUT_BF16)
                        ((u16*)Cout)[(size_t)row * N_COLS + cg] = f2bf(v);
                    else
                        ((float*)Cout)[(size_t)row * N_COLS + cg] = v;
                }
            }
        }
    }
}

// ---------------------------------------------------------------------------
// Host launch
// ---------------------------------------------------------------------------
extern "C" void kernel_launch(void* const* d_in, const int* in_sizes, int n_in,
                              void* d_out, int out_size, void* d_ws, size_t ws_size,
                              hipStream_t stream) {
    const float* x   = (const float*)d_in[0];
    const int*   src = (const int*)d_in[1];
    const int*   dst = (const int*)d_in[2];
    const float* W1  = (const float*)d_in[3];
    const float* b1  = (const float*)d_in[4];
    const float* W2  = (const float*)d_in[5];
    const float* b2  = (const float*)d_in[6];
    float* out = (float*)d_out;

    char* ws = (char*)d_ws;
    size_t off = 0;
    auto carve = [&](size_t bytes) {
        char* p = ws + off;
        off = (off + bytes + 255) & ~(size_t)255;
        return p;
    };
    int*   deg     = (int*)carve(sizeof(int) * N_NODES);
    int*   cursor  = (int*)carve(sizeof(int) * N_NODES);   // adjacent to deg -> 1 memset
    int*   row_ptr = (int*)carve(sizeof(int) * (N_NODES + 1));
    int*   part    = (int*)carve(sizeof(int) * 256);
    float* inv_deg = (float*)carve(sizeof(float) * N_NODES);
    int*   col     = (int*)carve(sizeof(int) * N_EDGES);
    u16*   xb      = (u16*)carve(sizeof(u16) * (size_t)M_PAD * F_IN);
    u16*   xnb     = (u16*)carve(sizeof(u16) * (size_t)M_PAD * F_IN);
    u16*   h1b     = (u16*)carve(sizeof(u16) * (size_t)M_PAD * F_HID);
    u16*   h1nb    = (u16*)carve(sizeof(u16) * (size_t)M_PAD * F_HID);
    u16*   W1t     = (u16*)carve(sizeof(u16) * 256 * 256);
    u16*   W2t     = (u16*)carve(sizeof(u16) * 256 * 512);

    // --- CSR build ---
    hipMemsetAsync(deg, 0, ((char*)row_ptr - (char*)deg), stream);  // deg + cursor
    deg_kernel<<<dim3((N_EDGES + 255) / 256), 256, 0, stream>>>(dst, deg);
    block_sum_kernel<<<dim3(NB_SCAN), 256, 0, stream>>>(deg, part);
    part_scan_kernel<<<dim3(1), 256, 0, stream>>>(part, row_ptr);
    row_ptr_kernel<<<dim3(NB_SCAN), 256, 0, stream>>>(deg, part, row_ptr, inv_deg);
    fill_kernel<<<dim3((N_EDGES + 255) / 256), 256, 0, stream>>>(src, dst, row_ptr, cursor, col);

    // --- bf16 conversions ---
    f2bf_kernel<<<dim3((N_NODES * F_IN / 4 + 255) / 256), 256, 0, stream>>>(x, xb, N_NODES * F_IN / 4);
    wtrans<256><<<dim3(256), 256, 0, stream>>>(W1, W1t);
    wtrans<512><<<dim3(256), 256, 0, stream>>>(W2, W2t);

    // --- Layer 1 ---
    agg_mean_bf16<F_IN><<<dim3((N_NODES + 15) / 16), 256, 0, stream>>>(xb, row_ptr, col, inv_deg, xnb);
    gemm_bt_wide<128, true><<<dim3(M_PAD / 64), 256, 0, stream>>>(xb, xnb, W1t, b1, h1b, N_NODES);

    // --- Layer 2 ---
    agg_mean_bf16<F_HID><<<dim3((N_NODES + 7) / 8), 256, 0, stream>>>(h1b, row_ptr, col, inv_deg, h1nb);
    gemm_bt_wide<256, false><<<dim3(M_PAD / 64), 256, 0, stream>>>(h1b, h1nb, W2t, b2, out, N_NODES);
}